// Round 3
// baseline (108.635 us; speedup 1.0000x reference)
//
#include <hip/hip_runtime.h>

#define W 126
#define NPIX 15876      // 126*126
#define NQUAD 3969      // NPIX/4
#define NB 16
#define NCH 8
#define NCLS 100
#define NYCH 10         // class chunks
#define CCHUNK 10       // classes per chunk
#define NBLK_A (249 * NYCH)   // 2490 partial blocks

// ws layout (floats): acc[0..255], MT[256..256+49*52), partials at 4096..
#define WS_ACC_OFF 0
#define WS_MT_OFF 256
#define WS_PART_OFF 4096

// ---------------------------------------------------------------------------
// Kernel A: contract logits over classes with (sigma_x, sigma_y, opacity, rho)
// and reduce into 196 accumulators keyed by slot = (y%7)*7 + (x%7).
// Thread owns one float4 pixel-quad x 10 classes; all 10 loads issued into
// registers up front (round-1 kernel had VGPR=32 -> ~serial load chain).
// ---------------------------------------------------------------------------
__global__ __launch_bounds__(256) void ga_reduce(
    const float* __restrict__ logits,
    const float* __restrict__ sx, const float* __restrict__ sy,
    const float* __restrict__ op, const float* __restrict__ rho,
    float* __restrict__ part) {
  __shared__ float s_par[4][NCLS];
  __shared__ float s_acc[196];
  const int t = threadIdx.x;
  for (int i = t; i < NCLS; i += 256) {
    s_par[0][i] = sx[i];
    s_par[1][i] = sy[i];
    s_par[2][i] = op[i];
    s_par[3][i] = rho[i];
  }
  for (int i = t; i < 196; i += 256) s_acc[i] = 0.f;
  __syncthreads();

  const int q = blockIdx.x * 256 + t;
  if (q < NB * NQUAD) {
    const int b  = q / NQUAD;
    const int pq = q - b * NQUAD;
    const float4* base = reinterpret_cast<const float4*>(logits) +
                         (size_t)b * NCLS * NQUAD + pq;
    const int c0 = blockIdx.y * CCHUNK;

    float4 v[CCHUNK];
#pragma unroll
    for (int cc = 0; cc < CCHUNK; ++cc)
      v[cc] = base[(size_t)(c0 + cc) * NQUAD];

    float a[4][4];
#pragma unroll
    for (int k = 0; k < 4; ++k)
#pragma unroll
      for (int j = 0; j < 4; ++j) a[k][j] = 0.f;

#pragma unroll
    for (int cc = 0; cc < CCHUNK; ++cc) {
      const float4 vv = v[cc];
#pragma unroll
      for (int k = 0; k < 4; ++k) {
        const float pk = s_par[k][c0 + cc];
        a[k][0] += vv.x * pk;
        a[k][1] += vv.y * pk;
        a[k][2] += vv.z * pk;
        a[k][3] += vv.w * pk;
      }
    }

    const int pix = pq * 4;
    int yy = pix / W;
    int xx = pix - yy * W;
#define PUSH(J)                                                      \
    {                                                                \
      const int slot = (yy % 7) * 7 + (xx % 7);                      \
      atomicAdd(&s_acc[slot],       a[0][J]);                        \
      atomicAdd(&s_acc[49 + slot],  a[1][J]);                        \
      atomicAdd(&s_acc[98 + slot],  a[2][J]);                        \
      atomicAdd(&s_acc[147 + slot], a[3][J]);                        \
      if (++xx == W) { xx = 0; ++yy; }                               \
    }
    PUSH(0) PUSH(1) PUSH(2) PUSH(3)
#undef PUSH
  }
  __syncthreads();
  float* my = part + (size_t)(blockIdx.y * 249 + blockIdx.x) * 196;
  for (int i = t; i < 196; i += 256) my[i] = s_acc[i];
}

// ---------------------------------------------------------------------------
// Kernel A2: sum the 2490 per-block partials for each of the 196 accumulators.
// ---------------------------------------------------------------------------
__global__ __launch_bounds__(256) void ga_final(const float* __restrict__ part,
                                                float* __restrict__ acc) {
  __shared__ float red[256];
  const int r = blockIdx.x;   // 0..195
  const int t = threadIdx.x;
  float s = 0.f;
  for (int j = t; j < NBLK_A; j += 256) s += part[(size_t)j * 196 + r];
  red[t] = s;
  __syncthreads();
#pragma unroll
  for (int off = 128; off; off >>= 1) {
    if (t < off) red[t] += red[t + off];
    __syncthreads();
  }
  if (t == 0) acc[r] = red[0];
}

// ---------------------------------------------------------------------------
// Kernel B: per-point gaussian kernel build + bilinear shift + opacity weight.
// Writes MT[p*52 + q] = wop[p] * kt[p][q]  (row per POINT p, contiguous in q
// so gc_splat's uniform row reads scalarize). Rows padded to 52 floats.
// ---------------------------------------------------------------------------
__global__ __launch_bounds__(64) void gb_build(const float* __restrict__ acc,
                                               float* __restrict__ MT) {
  __shared__ float s_kern[49][49];  // padded 7x7 kernel per point
  const int p = threadIdx.x;
  for (int i = p; i < 49; i += 64) {
    MT[i * 52 + 49] = 0.f;
    MT[i * 52 + 50] = 0.f;
    MT[i * 52 + 51] = 0.f;
  }
  if (p < 49) {
    const float inv = 1.0f / 5184.0f;   // mean over BL = 16*18*18
    const float wsx = acc[p]        * inv;
    const float wsy = acc[49 + p]   * inv;
    const float wop = acc[98 + p]   * inv;
    const float wrh = acc[147 + p]  * inv;
    const float av = wsx * wsx + 1e-5f;
    const float dv = wsy * wsy + 1e-5f;
    const float bv = wrh * wsx * wsy;
    const float det = av * dv - bv * bv;
    const float norm = 1.0f / (6.283185307179586f * sqrtf(det));
    float tmp[5][5];
    float mx = 0.f;
#pragma unroll
    for (int i = 0; i < 5; ++i) {
      const float gx = -5.0f + 2.5f * (float)i;
#pragma unroll
      for (int j = 0; j < 5; ++j) {
        const float gy = -5.0f + 2.5f * (float)j;
        const float z = -0.5f * (dv*gx*gx - 2.0f*bv*gx*gy + av*gy*gy) / det;
        const float v = expf(z) * norm;
        tmp[i][j] = v;
        mx = fmaxf(mx, v);
      }
    }
    const float rmx = 1.0f / mx;
#pragma unroll
    for (int i = 0; i < 49; ++i) s_kern[p][i] = 0.f;
#pragma unroll
    for (int i = 0; i < 5; ++i)
#pragma unroll
      for (int j = 0; j < 5; ++j)
        s_kern[p][(i + 1) * 7 + (j + 1)] = tmp[i][j] * rmx;

    // bilinear shift (grid_sample, zeros padding, pure translation)
    const int yp = p / 7, xp = p % 7;
    const float tx = (1.0f - (2.0f * (float)xp) / 7.0f) * 3.0f;
    const float ty = (1.0f - (2.0f * (float)yp) / 7.0f) * 3.0f;
    for (int i = 0; i < 7; ++i) {
      const float yq  = (float)i + ty;
      const float y0f = floorf(yq);
      const float fy  = yq - y0f;
      const int   y0  = (int)y0f;
      for (int j = 0; j < 7; ++j) {
        const float xq  = (float)j + tx;
        const float x0f = floorf(xq);
        const float fx  = xq - x0f;
        const int   x0  = (int)x0f;
        float v = 0.f;
        for (int dy = 0; dy < 2; ++dy) {
          const int yi = y0 + dy;
          if (yi < 0 || yi > 6) continue;
          const float wy = dy ? fy : (1.0f - fy);
          for (int dx = 0; dx < 2; ++dx) {
            const int xi = x0 + dx;
            if (xi < 0 || xi > 6) continue;
            const float wx = dx ? fx : (1.0f - fx);
            v += wy * wx * s_kern[p][yi * 7 + xi];
          }
        }
        MT[p * 52 + (i * 7 + j)] = wop * v;
      }
    }
  }
}

// ---------------------------------------------------------------------------
// Kernel C: splat. One THREAD per (plane, patch): 49 outputs in registers,
// M rows are wave-uniform reads (scalarize to s_load / K$-hit), feat value
// read once per p. 2401 f32 FMAs per thread; no LDS at all.
// ---------------------------------------------------------------------------
__global__ __launch_bounds__(64) void gc_splat(
    const float* __restrict__ feat, const float* __restrict__ MT,
    float* __restrict__ out) {
  const int idx   = blockIdx.x * 64 + threadIdx.x;   // 0..41471
  const int plane = idx / 324;                       // 128 planes
  const int pt    = idx - plane * 324;
  const int prow  = pt / 18;
  const int pcol  = pt - prow * 18;
  const size_t off = (size_t)plane * NPIX + (size_t)prow * 7 * W + pcol * 7;
  const float* src = feat + off;

  float acc[49];
#pragma unroll
  for (int qq = 0; qq < 49; ++qq) acc[qq] = 0.f;

  for (int i = 0; i < 7; ++i) {
    for (int j = 0; j < 7; ++j) {
      const float fp = src[i * W + j];
      const float* row = MT + (i * 7 + j) * 52;   // wave-uniform address
#pragma unroll
      for (int qq = 0; qq < 49; ++qq)
        acc[qq] = fmaf(fp, row[qq], acc[qq]);
    }
  }

  float* dst = out + off;
#pragma unroll
  for (int i = 0; i < 7; ++i)
#pragma unroll
    for (int j = 0; j < 7; ++j)
      dst[i * W + j] = acc[i * 7 + j];
}

extern "C" void kernel_launch(void* const* d_in, const int* in_sizes, int n_in,
                              void* d_out, int out_size, void* d_ws, size_t ws_size,
                              hipStream_t stream) {
  const float* feat   = (const float*)d_in[0];
  const float* logits = (const float*)d_in[1];
  const float* sx     = (const float*)d_in[2];
  const float* sy     = (const float*)d_in[3];
  const float* op     = (const float*)d_in[4];
  const float* rho    = (const float*)d_in[5];
  float* outp = (float*)d_out;
  float* ws   = (float*)d_ws;
  float* acc  = ws + WS_ACC_OFF;      // 196 floats
  float* MT   = ws + WS_MT_OFF;       // 49*52 floats
  float* part = ws + WS_PART_OFF;     // 2490*196 floats (~1.95 MB)

  dim3 gA((NB * NQUAD + 255) / 256, NYCH);   // 249 x 10 class-chunks
  ga_reduce<<<gA, 256, 0, stream>>>(logits, sx, sy, op, rho, part);
  ga_final<<<196, 256, 0, stream>>>(part, acc);
  gb_build<<<1, 64, 0, stream>>>(acc, MT);
  gc_splat<<<(NB * NCH * 324) / 64, 64, 0, stream>>>(feat, MT, outp);
}

// Round 4
// 61.590 us; speedup vs baseline: 1.7638x; 1.7638x over previous
//
#include <hip/hip_runtime.h>

#define W 126
#define NPIX 15876      // 126*126
#define NB 16
#define NCH 8
#define NCLS 100

#define GR 3            // rows per wave (same residue)
#define CC 10           // classes per chunk
#define NYCH 10         // class chunks
#define NWAVES (NYCH * NB * 7 * 6)   // 6720
#define NBLK_A (NWAVES / 4)          // 1680

// ws layout (floats): acc[0..255], MT[256..256+49*52), partials at 4096..
#define WS_ACC_OFF 0
#define WS_MT_OFF 256
#define WS_PART_OFF 4096

// ---------------------------------------------------------------------------
// Kernel A: binned contraction of logits with (sigma_x, sigma_y, op, rho).
// Wave handles GR rows that share residue m = y%7 (y = m + 7t), for CC
// classes. Lane l owns pixels 2l,2l+1 (float2, fully coalesced); their x%7
// is lane-fixed, so accumulation is 8 registers — NO LDS atomics in the hot
// path (round-3's 16 atomicAdds/thread were the 72us compute-bound stall).
// Block reduce: regs -> LDS, 112 reducer threads x 18 known indices,
// 112 LDS atomics/block total, one contiguous 196-float partial per block.
// ---------------------------------------------------------------------------
__global__ __launch_bounds__(256) void ga_reduce(
    const float* __restrict__ logits,
    const float* __restrict__ sx, const float* __restrict__ sy,
    const float* __restrict__ op, const float* __restrict__ rho,
    float* __restrict__ part) {
  __shared__ float s_data[4][64][8];
  __shared__ float s_bin[196];
  __shared__ int   s_m[4];
  const int t    = threadIdx.x;
  const int w    = t >> 6;
  const int lane = t & 63;

  for (int i = t; i < 196; i += 256) s_bin[i] = 0.f;

  const int wid = blockIdx.x * 4 + w;      // 0..6719
  const int cy  = wid / 672;               // class chunk 0..9
  int rem = wid - cy * 672;
  const int b   = rem / 42;                // batch 0..15
  rem -= b * 42;
  const int m   = rem / 6;                 // row residue 0..6
  const int yg  = rem - m * 6;             // row group 0..5
  if (lane == 0) s_m[w] = m;

  float a[4][2];
#pragma unroll
  for (int k = 0; k < 4; ++k) { a[k][0] = 0.f; a[k][1] = 0.f; }

  if (lane < 63) {
    const int c0 = cy * CC;
#pragma unroll
    for (int r = 0; r < GR; ++r) {
      const int y = m + 7 * (yg * GR + r);
      const float2* rowb = reinterpret_cast<const float2*>(
          logits + ((size_t)(b * NCLS) * W + y) * W) + lane;
      float2 v[CC];
#pragma unroll
      for (int cc = 0; cc < CC; ++cc)
        v[cc] = rowb[(size_t)(c0 + cc) * (NPIX / 2)];
#pragma unroll
      for (int cc = 0; cc < CC; ++cc) {
        const int c = c0 + cc;              // wave-uniform -> s_load params
        const float p0 = sx[c], p1 = sy[c], p2 = op[c], p3 = rho[c];
        a[0][0] += v[cc].x * p0; a[0][1] += v[cc].y * p0;
        a[1][0] += v[cc].x * p1; a[1][1] += v[cc].y * p1;
        a[2][0] += v[cc].x * p2; a[2][1] += v[cc].y * p2;
        a[3][0] += v[cc].x * p3; a[3][1] += v[cc].y * p3;
      }
    }
  }

#pragma unroll
  for (int k = 0; k < 4; ++k) {
    s_data[w][lane][k * 2]     = a[k][0];
    s_data[w][lane][k * 2 + 1] = a[k][1];
  }
  __syncthreads();

  if (t < 112) {                       // (wave, param, x-residue) reducers
    const int ww = t / 28;
    const int k  = (t % 28) / 7;
    const int n  = t % 7;
    float s = 0.f;
#pragma unroll
    for (int j = 0; j < 18; ++j) {     // pixels p = n + 7j of the row
      const int p = n + 7 * j;
      s += s_data[ww][p >> 1][k * 2 + (p & 1)];
    }
    atomicAdd(&s_bin[k * 49 + s_m[ww] * 7 + n], s);
  }
  __syncthreads();

  float* my = part + (size_t)blockIdx.x * 196;
  for (int i = t; i < 196; i += 256) my[i] = s_bin[i];
}

// ---------------------------------------------------------------------------
// Kernel A2: sum 1680 partials. 49 blocks x 4 bins, coalesced float4 reads.
// ---------------------------------------------------------------------------
__global__ __launch_bounds__(256) void ga_final(const float* __restrict__ part,
                                                float* __restrict__ acc) {
  __shared__ float4 red[256];
  const int h = blockIdx.x;            // 0..48 -> bins 4h..4h+3
  const int t = threadIdx.x;
  float4 s = make_float4(0.f, 0.f, 0.f, 0.f);
  for (int j = t; j < NBLK_A; j += 256) {
    const float4 v =
        *reinterpret_cast<const float4*>(part + (size_t)j * 196 + h * 4);
    s.x += v.x; s.y += v.y; s.z += v.z; s.w += v.w;
  }
  red[t] = s;
  __syncthreads();
#pragma unroll
  for (int off = 128; off; off >>= 1) {
    if (t < off) {
      red[t].x += red[t + off].x; red[t].y += red[t + off].y;
      red[t].z += red[t + off].z; red[t].w += red[t + off].w;
    }
    __syncthreads();
  }
  if (t == 0) *reinterpret_cast<float4*>(acc + h * 4) = red[0];
}

// ---------------------------------------------------------------------------
// Kernel B: per-point gaussian build + bilinear shift + opacity weight.
// Writes MT[q*52 + p] = wop[p] * kt[p][q] (q-major rows, padded to 52).
// ---------------------------------------------------------------------------
__global__ __launch_bounds__(64) void gb_build(const float* __restrict__ acc,
                                               float* __restrict__ MT) {
  __shared__ float s_kern[49][49];
  const int p = threadIdx.x;
  for (int i = p; i < 49; i += 64) {
    MT[i * 52 + 49] = 0.f;
    MT[i * 52 + 50] = 0.f;
    MT[i * 52 + 51] = 0.f;
  }
  if (p < 49) {
    const float inv = 1.0f / 5184.0f;   // mean over BL = 16*18*18
    const float wsx = acc[p]        * inv;
    const float wsy = acc[49 + p]   * inv;
    const float wop = acc[98 + p]   * inv;
    const float wrh = acc[147 + p]  * inv;
    const float av = wsx * wsx + 1e-5f;
    const float dv = wsy * wsy + 1e-5f;
    const float bv = wrh * wsx * wsy;
    const float det = av * dv - bv * bv;
    const float norm = 1.0f / (6.283185307179586f * sqrtf(det));
    float tmp[5][5];
    float mx = 0.f;
#pragma unroll
    for (int i = 0; i < 5; ++i) {
      const float gx = -5.0f + 2.5f * (float)i;
#pragma unroll
      for (int j = 0; j < 5; ++j) {
        const float gy = -5.0f + 2.5f * (float)j;
        const float z = -0.5f * (dv*gx*gx - 2.0f*bv*gx*gy + av*gy*gy) / det;
        const float v = expf(z) * norm;
        tmp[i][j] = v;
        mx = fmaxf(mx, v);
      }
    }
    const float rmx = 1.0f / mx;
#pragma unroll
    for (int i = 0; i < 49; ++i) s_kern[p][i] = 0.f;
#pragma unroll
    for (int i = 0; i < 5; ++i)
#pragma unroll
      for (int j = 0; j < 5; ++j)
        s_kern[p][(i + 1) * 7 + (j + 1)] = tmp[i][j] * rmx;

    const int yp = p / 7, xp = p % 7;
    const float tx = (1.0f - (2.0f * (float)xp) / 7.0f) * 3.0f;
    const float ty = (1.0f - (2.0f * (float)yp) / 7.0f) * 3.0f;
    for (int i = 0; i < 7; ++i) {
      const float yq  = (float)i + ty;
      const float y0f = floorf(yq);
      const float fy  = yq - y0f;
      const int   y0  = (int)y0f;
      for (int j = 0; j < 7; ++j) {
        const float xq  = (float)j + tx;
        const float x0f = floorf(xq);
        const float fx  = xq - x0f;
        const int   x0  = (int)x0f;
        float v = 0.f;
        for (int dy = 0; dy < 2; ++dy) {
          const int yi = y0 + dy;
          if (yi < 0 || yi > 6) continue;
          const float wy = dy ? fy : (1.0f - fy);
          for (int dx = 0; dx < 2; ++dx) {
            const int xi = x0 + dx;
            if (xi < 0 || xi > 6) continue;
            const float wx = dx ? fx : (1.0f - fx);
            v += wy * wx * s_kern[p][yi * 7 + xi];
          }
        }
        MT[(i * 7 + j) * 52 + p] = wop * v;
      }
    }
  }
}

// ---------------------------------------------------------------------------
// Kernel C (round-2 version): one block per (plane, patch-row) strip.
// out[q] = dot49(feat_patch, MT_row[q]); both staged in LDS, float4 reads.
// ---------------------------------------------------------------------------
__global__ __launch_bounds__(256) void gc_splat(
    const float* __restrict__ feat, const float* __restrict__ MT,
    float* __restrict__ out) {
  __shared__ __align__(16) float s_mt[49 * 52];
  __shared__ __align__(16) float s_fp[18 * 52];
  const int t = threadIdx.x;
  for (int i = t; i < 49 * 52; i += 256) s_mt[i] = MT[i];
  const int blk   = blockIdx.x;           // plane*18 + patch_row
  const int plane = blk / 18;
  const int pr    = blk - plane * 18;
  const float* src = feat + (size_t)plane * NPIX + (size_t)pr * 7 * W;
  for (int i = t; i < 882; i += 256) {
    const int py = i / W;
    const int xx = i - py * W;
    const int pc = xx / 7;
    const int px = xx - pc * 7;
    s_fp[pc * 52 + py * 7 + px] = src[i];
  }
  __syncthreads();
  float* dst = out + (size_t)plane * NPIX + (size_t)pr * 7 * W;
  for (int i = t; i < 882; i += 256) {
    const int yy = i / W;
    const int xx = i - yy * W;
    const int pc = xx / 7;
    const int q  = yy * 7 + (xx - pc * 7);
    const float4* mv = reinterpret_cast<const float4*>(s_mt + q * 52);
    const float4* fv = reinterpret_cast<const float4*>(s_fp + pc * 52);
    float s = 0.f;
#pragma unroll
    for (int r = 0; r < 12; ++r) {
      const float4 mm = mv[r];
      const float4 ff = fv[r];
      s += ff.x * mm.x + ff.y * mm.y + ff.z * mm.z + ff.w * mm.w;
    }
    s += s_fp[pc * 52 + 48] * s_mt[q * 52 + 48];
    dst[i] = s;
  }
}

extern "C" void kernel_launch(void* const* d_in, const int* in_sizes, int n_in,
                              void* d_out, int out_size, void* d_ws, size_t ws_size,
                              hipStream_t stream) {
  const float* feat   = (const float*)d_in[0];
  const float* logits = (const float*)d_in[1];
  const float* sx     = (const float*)d_in[2];
  const float* sy     = (const float*)d_in[3];
  const float* op     = (const float*)d_in[4];
  const float* rho    = (const float*)d_in[5];
  float* outp = (float*)d_out;
  float* ws   = (float*)d_ws;
  float* acc  = ws + WS_ACC_OFF;      // 196 floats
  float* MT   = ws + WS_MT_OFF;       // 49*52 floats
  float* part = ws + WS_PART_OFF;     // 1680*196 floats (~1.3 MB)

  ga_reduce<<<NBLK_A, 256, 0, stream>>>(logits, sx, sy, op, rho, part);
  ga_final<<<49, 256, 0, stream>>>(part, acc);
  gb_build<<<1, 64, 0, stream>>>(acc, MT);
  gc_splat<<<NB * NCH * 18, 256, 0, stream>>>(feat, MT, outp);
}